// Round 1
// baseline (347.301 us; speedup 1.0000x reference)
//
#include <hip/hip_runtime.h>

typedef __bf16 bfx8 __attribute__((ext_vector_type(8)));
typedef float f32x4 __attribute__((ext_vector_type(4)));
typedef unsigned short u16x8 __attribute__((ext_vector_type(8)));
typedef unsigned short u16x4 __attribute__((ext_vector_type(4)));

// Geometry: x (8, 256, 16384) fp32; mem (200, 256) fp32; out (8, 256, 16384) fp32.
// M padded 200 -> 256 (padded mem rows are zero, masked to p=0 in softmax).

// ---------- prep: mem -> bf16 hi/lo (row-major) + bf16 transposed ----------
__global__ __launch_bounds__(256) void prep_mem(const float* __restrict__ mem,
                                                unsigned short* __restrict__ Mh,
                                                unsigned short* __restrict__ Ml,
                                                unsigned short* __restrict__ MT) {
    const int s = blockIdx.x;    // 0..255 (slot, padded)
    const int c = threadIdx.x;   // 0..255 (channel)
    const float v = (s < 200) ? mem[s * 256 + c] : 0.0f;
    const __bf16 hi = (__bf16)v;
    const __bf16 lo = (__bf16)(v - (float)hi);
    const unsigned short hib = __builtin_bit_cast(unsigned short, hi);
    const unsigned short lob = __builtin_bit_cast(unsigned short, lo);
    Mh[s * 256 + c] = hib;   // [slot][c]
    Ml[s * 256 + c] = lob;   // [slot][c]
    MT[c * 256 + s] = hib;   // [c][slot]
}

// ---------- fused: scores (3-pass split bf16 MFMA) -> softmax -> PV ----------
__global__ __launch_bounds__(256, 2) void fused_mem_attn(
        const float* __restrict__ x,
        const unsigned short* __restrict__ Mh,
        const unsigned short* __restrict__ Ml,
        const unsigned short* __restrict__ MT,
        float* __restrict__ out) {
    // Per-wave P^T staging buffer: [16 tokens][256 slots] bf16, XOR-swizzled
    // in 8-element (16B) blocks: block' = block ^ (token & 7).
    __shared__ unsigned short PT[4][16 * 256];

    const int tid  = threadIdx.x;
    const int wave = tid >> 6;
    const int lane = tid & 63;
    const int t16  = lane & 15;        // token-in-wave (B col / A row index)
    const int h    = (lane >> 4) & 3;  // lane group

    const long gtok = (long)blockIdx.x * 64 + wave * 16;  // wave's first token
    const int  b    = (int)(gtok >> 14);                  // 16384 tokens per batch
    const int  n    = (int)(gtok & 16383) + t16;          // spatial index
    const float* xb = x + ((long)b << 22) + n;            // x[b][0][n]

    // ---- load this lane's x channels as B-fragments (hi/lo bf16) ----
    // B[k=c][col=token]: lane holds col = lane&15, k = 8*(lane>>4)+j (+32*ks)
    bfx8 xh[8], xl[8];
    #pragma unroll
    for (int ks = 0; ks < 8; ++ks) {
        float v[8];
        #pragma unroll
        for (int j = 0; j < 8; ++j) {
            const int c = ks * 32 + h * 8 + j;
            v[j] = xb[(long)c << 14];
        }
        #pragma unroll
        for (int j = 0; j < 8; ++j) {
            const __bf16 hi = (__bf16)v[j];
            const __bf16 lo = (__bf16)(v[j] - (float)hi);
            xh[ks][j] = hi;
            xl[ks][j] = lo;
        }
    }

    // ---- scores: S^T[slot][token] = sum_c mem[slot][c] * x[c][token] ----
    f32x4 acc[16];
    #pragma unroll
    for (int tt = 0; tt < 16; ++tt) acc[tt] = (f32x4){0.f, 0.f, 0.f, 0.f};

    for (int ks = 0; ks < 8; ++ks) {
        __syncthreads();  // keep waves on the same 32KB mem slice (L1 reuse)
        const int c0 = ks * 32 + h * 8;
        #pragma unroll
        for (int tt = 0; tt < 16; ++tt) {
            const int slot = tt * 16 + t16;  // A row = lane&15
            const u16x8 ahu = *(const u16x8*)(Mh + slot * 256 + c0);
            const u16x8 alu = *(const u16x8*)(Ml + slot * 256 + c0);
            const bfx8 ah = __builtin_bit_cast(bfx8, ahu);
            const bfx8 al = __builtin_bit_cast(bfx8, alu);
            acc[tt] = __builtin_amdgcn_mfma_f32_16x16x32_bf16(ah, xh[ks], acc[tt], 0, 0, 0);
            acc[tt] = __builtin_amdgcn_mfma_f32_16x16x32_bf16(ah, xl[ks], acc[tt], 0, 0, 0);
            acc[tt] = __builtin_amdgcn_mfma_f32_16x16x32_bf16(al, xh[ks], acc[tt], 0, 0, 0);
        }
    }

    // ---- softmax over slots (per token = per lane&15 column) ----
    // C/D layout: col = lane&15 (token), row-in-tile = 4*h + r (slot)
    float m = -3.0e38f;
    #pragma unroll
    for (int tt = 0; tt < 16; ++tt)
        #pragma unroll
        for (int r = 0; r < 4; ++r) {
            const int sid = tt * 16 + h * 4 + r;
            if (sid < 200) m = fmaxf(m, acc[tt][r]);
        }
    m = fmaxf(m, __shfl_xor(m, 16, 64));
    m = fmaxf(m, __shfl_xor(m, 32, 64));

    float sum = 0.f;
    #pragma unroll
    for (int tt = 0; tt < 16; ++tt)
        #pragma unroll
        for (int r = 0; r < 4; ++r) {
            const int sid = tt * 16 + h * 4 + r;
            const float p = (sid < 200) ? __expf(acc[tt][r] - m) : 0.f;
            acc[tt][r] = p;
            sum += p;
        }
    sum += __shfl_xor(sum, 16, 64);
    sum += __shfl_xor(sum, 32, 64);
    const float inv = 1.f / sum;

    // ---- write P^T to swizzled LDS (bf16) ----
    unsigned short* ptw = &PT[wave][0];
    #pragma unroll
    for (int tt = 0; tt < 16; ++tt) {
        u16x4 pk;
        #pragma unroll
        for (int r = 0; r < 4; ++r) {
            const __bf16 pb = (__bf16)acc[tt][r];
            pk[r] = __builtin_bit_cast(unsigned short, pb);
        }
        const int sb  = tt * 2 + (h >> 1);        // 8-elem block of slot 16*tt+4*h
        const int sbs = sb ^ (t16 & 7);           // swizzle
        const int idx = t16 * 256 + sbs * 8 + (h & 1) * 4;
        *(u16x4*)(ptw + idx) = pk;
    }
    __syncthreads();

    // ---- PV: out^T[c][token] = sum_s memT[c][s] * P^T[s][token] ----
    f32x4 acc2[16];
    #pragma unroll
    for (int ct = 0; ct < 16; ++ct) acc2[ct] = (f32x4){0.f, 0.f, 0.f, 0.f};

    for (int ks = 0; ks < 8; ++ks) {
        const int sb  = ks * 4 + h;
        const int sbs = sb ^ (t16 & 7);
        const u16x8 pbu = *(const u16x8*)(ptw + t16 * 256 + sbs * 8);
        const bfx8  pb  = __builtin_bit_cast(bfx8, pbu);
        const int s0 = ks * 32 + h * 8;
        #pragma unroll
        for (int ct = 0; ct < 16; ++ct) {
            const u16x8 atu = *(const u16x8*)(MT + (ct * 16 + t16) * 256 + s0);
            const bfx8  at  = __builtin_bit_cast(bfx8, atu);
            acc2[ct] = __builtin_amdgcn_mfma_f32_16x16x32_bf16(at, pb, acc2[ct], 0, 0, 0);
        }
    }

    // ---- epilogue: normalize and store out[b][c][n] ----
    float* ob = out + ((long)b << 22) + n;
    #pragma unroll
    for (int ct = 0; ct < 16; ++ct)
        #pragma unroll
        for (int r = 0; r < 4; ++r) {
            const int c = ct * 16 + h * 4 + r;
            ob[(long)c << 14] = acc2[ct][r] * inv;
        }
}

extern "C" void kernel_launch(void* const* d_in, const int* in_sizes, int n_in,
                              void* d_out, int out_size, void* d_ws, size_t ws_size,
                              hipStream_t stream) {
    const float* x   = (const float*)d_in[0];
    const float* mem = (const float*)d_in[1];
    float* out = (float*)d_out;

    unsigned short* Mh = (unsigned short*)d_ws;   // [256][256] bf16 hi
    unsigned short* Ml = Mh + 256 * 256;          // [256][256] bf16 lo
    unsigned short* MT = Ml + 256 * 256;          // [256][256] bf16 hi, transposed [c][slot]

    prep_mem<<<dim3(256), dim3(256), 0, stream>>>(mem, Mh, Ml, MT);

    // 131072 tokens / 64 per block
    fused_mem_attn<<<dim3(2048), dim3(256), 0, stream>>>(x, Mh, Ml, MT, out);
}

// Round 2
// 102.240 us; speedup vs baseline: 3.3969x; 3.3969x over previous
//
#include <hip/hip_runtime.h>

typedef __bf16 bfx8 __attribute__((ext_vector_type(8)));
typedef float f32x4 __attribute__((ext_vector_type(4)));

#define MFMA16(a, b, c) __builtin_amdgcn_mfma_f32_16x16x32_bf16((a), (b), (c), 0, 0, 0)

#define GLOAD16(gp, lp)                                                        \
  __builtin_amdgcn_global_load_lds(                                            \
      (const __attribute__((address_space(1))) unsigned int*)(gp),             \
      (__attribute__((address_space(3))) unsigned int*)(lp), 16, 0, 0)

// Geometry: x (8, 256, 16384) fp32; mem (200, 256) fp32; out (8, 256, 16384) fp32.
// Slots padded 200 -> 256 with zero rows.

// ---------------- prep: mem -> bf16 hi/lo + permuted-transposed hi ----------------
// MTp[c][kidx] = hi(mem[sigma(kidx)][c]) where sigma(32ks+8h+j) = 32ks + 16*(j>>2) + 4h + (j&3).
// This makes the PV B-operand a pure in-register repack of the score accumulators.
__global__ __launch_bounds__(256) void prep_mem(const float* __restrict__ mem,
                                                unsigned short* __restrict__ Mh,
                                                unsigned short* __restrict__ Ml,
                                                unsigned short* __restrict__ MTp) {
  const int s = blockIdx.x;   // slot (padded)
  const int c = threadIdx.x;  // channel
  const float v = (s < 200) ? mem[s * 256 + c] : 0.0f;
  const __bf16 hi = (__bf16)v;
  const __bf16 lo = (__bf16)(v - (float)hi);
  const unsigned short hib = __builtin_bit_cast(unsigned short, hi);
  const unsigned short lob = __builtin_bit_cast(unsigned short, lo);
  Mh[s * 256 + c] = hib;
  Ml[s * 256 + c] = lob;
  // invert sigma: s = 32ks + 16t + 4h + r  ->  kidx = 32ks + 8h + 4t + r
  const int ks = s >> 5, w = s & 31;
  const int t = w >> 4, hh = (w >> 2) & 3, rr = w & 3;
  MTp[c * 256 + (ks * 32 + hh * 8 + t * 4 + rr)] = hib;
}

// ---------------- fused kernel ----------------
// Block = 4 waves x 32 tokens = 128 tokens. Grid = 1024.
// LDS 64KB: score phase = 2 x (16KB Mh-slice + 16KB Ml-slice) dbuf;
// PV phase reuses the pool as 4 rotating 16KB MTp-slice buffers.
__global__ __launch_bounds__(256, 2) void fused_mem_attn(
    const float* __restrict__ x, const unsigned short* __restrict__ Mh,
    const unsigned short* __restrict__ Ml, const unsigned short* __restrict__ MTp,
    float* __restrict__ out) {
  __shared__ alignas(128) char lds[65536];

  const int tid = threadIdx.x;
  const int wave = tid >> 6;
  const int lane = tid & 63;
  const int t16 = lane & 15;
  const int h = lane >> 4;

  // Staging: thread owns physical 16B-blocks P = it*256+tid; fetches logical
  // L = P ^ ((P>>3)&7)  (involution) so LDS content is XOR-swizzled while the
  // global_load_lds destination stays linear.
  int srcOff[4];
#pragma unroll
  for (int it = 0; it < 4; ++it) {
    const int P = it * 256 + tid;
    const int L = P ^ ((P >> 3) & 7);
    srcOff[it] = (L >> 2) * 512 + (L & 3) * 16;  // byte offset in a [256][64B] matrix
  }

  // Reader-side swizzled block byte offset within a 64-block (1KB) row-tile.
  const int q16 = ((((t16 << 2) + h) ^ (t16 >> 1)) << 4);

  const long gtok0 = (long)blockIdx.x * 128 + (long)(wave * 32);
  const int b = (int)(gtok0 >> 14);
  const int n0 = (int)(gtok0 & 16383);
  const float* xb0 = x + ((long)b << 22) + n0 + t16;
  const float* xb1 = xb0 + 16;

  const char* MhB = (const char*)Mh;
  const char* MlB = (const char*)Ml;
  const char* MTB = (const char*)MTp;

#define STAGE_SCORE(ks)                                                        \
  {                                                                            \
    char* dst_ = lds + (((ks) & 1) * 32768);                                   \
    _Pragma("unroll") for (int it = 0; it < 4; ++it) {                         \
      const int pOff_ = (it * 256 + tid) * 16;                                 \
      GLOAD16(MhB + srcOff[it] + (ks) * 64, dst_ + pOff_);                     \
      GLOAD16(MlB + srcOff[it] + (ks) * 64, dst_ + 16384 + pOff_);             \
    }                                                                          \
  }

#define STAGE_PV(k)                                                            \
  {                                                                            \
    char* dst_ = lds + (((k) & 3) * 16384);                                    \
    _Pragma("unroll") for (int it = 0; it < 4; ++it) {                         \
      GLOAD16(MTB + srcOff[it] + (k) * 64, dst_ + (it * 256 + tid) * 16);      \
    }                                                                          \
  }

#define XLOAD(ks)                                                              \
  _Pragma("unroll") for (int j = 0; j < 8; ++j) {                              \
    const long coff_ = (long)((ks) * 32 + h * 8 + j) << 14;                    \
    xr[(ks) & 1][0][j] = xb0[coff_];                                           \
    xr[(ks) & 1][1][j] = xb1[coff_];                                           \
  }

  float xr[2][2][8];
  f32x4 acc[14][2] = {};  // acc[13] stays exactly 0 (slots 208..223 are zero rows)

  STAGE_SCORE(0);
  XLOAD(0);

  // ---- score phase: S^T[slot][token], 3-pass hi/lo split ----
#pragma unroll
  for (int ks = 0; ks < 8; ++ks) {
    __syncthreads();  // drains prev-iter staging (m97 pattern)
    if (ks < 7) {
      STAGE_SCORE(ks + 1);
      XLOAD(ks + 1);
    } else {
      STAGE_PV(0);
    }
    bfx8 xh0, xl0, xh1, xl1;
#pragma unroll
    for (int j = 0; j < 8; ++j) {
      const float f0 = xr[ks & 1][0][j];
      const float f1 = xr[ks & 1][1][j];
      const __bf16 h0 = (__bf16)f0;
      const __bf16 h1 = (__bf16)f1;
      xh0[j] = h0;
      xl0[j] = (__bf16)(f0 - (float)h0);
      xh1[j] = h1;
      xl1[j] = (__bf16)(f1 - (float)h1);
    }
    const char* sb = lds + ((ks & 1) * 32768);
#pragma unroll
    for (int tt = 0; tt < 13; ++tt) {  // slots >= 208 are dead (padding)
      const bfx8 ah = *(const bfx8*)(sb + tt * 1024 + q16);
      const bfx8 al = *(const bfx8*)(sb + 16384 + tt * 1024 + q16);
      acc[tt][0] = MFMA16(ah, xh0, acc[tt][0]);
      acc[tt][1] = MFMA16(ah, xh1, acc[tt][1]);
      acc[tt][0] = MFMA16(al, xh0, acc[tt][0]);
      acc[tt][1] = MFMA16(al, xh1, acc[tt][1]);
      acc[tt][0] = MFMA16(ah, xl0, acc[tt][0]);
      acc[tt][1] = MFMA16(ah, xl1, acc[tt][1]);
    }
  }

  // ---- softmax over slots (per token column = lane&15); C row = 4h+r ----
  float inv0, inv1;
#pragma unroll
  for (int g = 0; g < 2; ++g) {
    float m = -3.0e38f;
#pragma unroll
    for (int tt = 0; tt < 12; ++tt)
#pragma unroll
      for (int r = 0; r < 4; ++r) m = fmaxf(m, acc[tt][g][r]);
#pragma unroll
    for (int r = 0; r < 4; ++r)
      if (192 + h * 4 + r < 200) m = fmaxf(m, acc[12][g][r]);
    m = fmaxf(m, __shfl_xor(m, 16, 64));
    m = fmaxf(m, __shfl_xor(m, 32, 64));
    float s = 0.f;
#pragma unroll
    for (int tt = 0; tt < 12; ++tt)
#pragma unroll
      for (int r = 0; r < 4; ++r) {
        const float p = __expf(acc[tt][g][r] - m);
        acc[tt][g][r] = p;
        s += p;
      }
#pragma unroll
    for (int r = 0; r < 4; ++r) {
      const bool ok = (192 + h * 4 + r) < 200;
      const float p = ok ? __expf(acc[12][g][r] - m) : 0.f;
      acc[12][g][r] = p;
      s += p;
    }
    s += __shfl_xor(s, 16, 64);
    s += __shfl_xor(s, 32, 64);
    if (g == 0) inv0 = 1.f / s;
    else        inv1 = 1.f / s;
  }

  // ---- repack P into PV B-fragments IN REGISTERS (sigma baked into MTp) ----
  bfx8 pb[7][2];
#pragma unroll
  for (int k = 0; k < 7; ++k)
#pragma unroll
    for (int g = 0; g < 2; ++g)
#pragma unroll
      for (int j = 0; j < 4; ++j) {
        pb[k][g][j] = (__bf16)acc[2 * k][g][j];
        pb[k][g][j + 4] = (__bf16)acc[2 * k + 1][g][j];
      }

  // ---- PV: out^T[c][token] = sum_kidx MTp[c][kidx] * P[sigma(kidx)][token] ----
  f32x4 acc2[16][2] = {};
#pragma unroll
  for (int k = 0; k < 7; ++k) {  // kidx >= 224 all-zero P -> skipped
    __syncthreads();
    if (k < 6) STAGE_PV(k + 1);
    const char* pv = lds + ((k & 3) * 16384);
#pragma unroll
    for (int ct = 0; ct < 16; ++ct) {
      const bfx8 at = *(const bfx8*)(pv + ct * 1024 + q16);
      acc2[ct][0] = MFMA16(at, pb[k][0], acc2[ct][0]);
      acc2[ct][1] = MFMA16(at, pb[k][1], acc2[ct][1]);
    }
  }

  // ---- epilogue: normalize, store out[b][c][n] ----
  float* ob = out + ((long)b << 22) + n0 + t16;
#pragma unroll
  for (int ct = 0; ct < 16; ++ct)
#pragma unroll
    for (int r = 0; r < 4; ++r) {
      const long o = (long)(ct * 16 + h * 4 + r) << 14;
      ob[o] = acc2[ct][0][r] * inv0;
      ob[o + 16] = acc2[ct][1][r] * inv1;
    }
#undef STAGE_SCORE
#undef STAGE_PV
#undef XLOAD
}

extern "C" void kernel_launch(void* const* d_in, const int* in_sizes, int n_in,
                              void* d_out, int out_size, void* d_ws, size_t ws_size,
                              hipStream_t stream) {
  const float* x = (const float*)d_in[0];
  const float* mem = (const float*)d_in[1];
  float* out = (float*)d_out;

  unsigned short* Mh = (unsigned short*)d_ws;  // [256][256] bf16 hi
  unsigned short* Ml = Mh + 256 * 256;         // [256][256] bf16 lo
  unsigned short* MTp = Ml + 256 * 256;        // [256][256] bf16 hi, [c][kidx] permuted

  prep_mem<<<dim3(256), dim3(256), 0, stream>>>(mem, Mh, Ml, MTp);
  fused_mem_attn<<<dim3(1024), dim3(256), 0, stream>>>(x, Mh, Ml, MTp, out);
}